// Round 15
// baseline (446.608 us; speedup 1.0000x reference)
//
#include <hip/hip_runtime.h>
#include <hip/hip_fp16.h>

static constexpr int N_NODES = 500000;
static constexpr int N_EDGES = 16000000;

typedef int  iv4 __attribute__((ext_vector_type(4)));
typedef unsigned int uv4 __attribute__((ext_vector_type(4)));

// ---------- fast-path geometry ----------
static constexpr int BUCKET_SHIFT = 9;                 // 512 nodes / bucket
static constexpr int BUCKET_NODES = 1 << BUCKET_SHIFT; // 512
static constexpr int NB = (N_NODES + BUCKET_NODES - 1) >> BUCKET_SHIFT; // 977
static constexpr int NBUCK = 1024;                     // padded pow2 for LDS arrays
static constexpr int CAP = 18432;                      // per-bucket global capacity (mean 16378)
static constexpr int CHUNK = 10000;                    // edges per bin-block
static constexpr int BLOCKS_A = N_EDGES / CHUNK;       // 1600
static constexpr int CAP_S = 16;                       // per-bucket LDS staging (mean 9.8; overflow -> slow path)

// ws layout (bytes) — identical to R5/R13 (proven)
static constexpr size_t XMP_OFF  = 0;                          // ushort4[N_NODES] = 4,000,000
static constexpr size_t SUMS_OFF = 4000000;                    // double[4]
static constexpr size_t FILL_OFF = 4000064;                    // int[1024]
static constexpr size_t REC_OFF  = 4194304;                    // u32[NB*CAP] = 72,030,208
static constexpr size_t WS_NEEDED = REC_OFF + (size_t)NB * CAP * 4;  // 76,224,512

// LDS packed-f16 atomic add: ds_pk_add_f16 (proven R13)
__device__ __forceinline__ void lds_pk_add_f16(unsigned int* gptr, unsigned int val) {
    unsigned addr = (unsigned)(size_t)(__attribute__((address_space(3))) unsigned int*)gptr;
    asm volatile("ds_pk_add_f16 %0, %1" :: "v"(addr), "v"(val) : "memory");
}

// =====================================================================
// FAST PATH
// =====================================================================

// xm(f16x4) = x @ M ; zero bucketFill and sums
__global__ void prep_kernel(const float* __restrict__ x,
                            const float* __restrict__ M,
                            ushort4* __restrict__ xmp,
                            int* __restrict__ bucketFill,
                            double* __restrict__ sums) {
    int i = blockIdx.x * blockDim.x + threadIdx.x;
    if (i < NBUCK) bucketFill[i] = 0;
    if (i == 0) { sums[0] = 0.0; sums[1] = 0.0; sums[2] = 0.0; }
    if (i < N_NODES) {
        float m00 = M[0], m01 = M[1], m02 = M[2];
        float m10 = M[3], m11 = M[4], m12 = M[5];
        float m20 = M[6], m21 = M[7], m22 = M[8];
        float x0 = x[i * 3 + 0], x1 = x[i * 3 + 1], x2 = x[i * 3 + 2];
        float v0 = x0 * m00 + x1 * m10 + x2 * m20;
        float v1 = x0 * m01 + x1 * m11 + x2 * m21;
        float v2 = x0 * m02 + x1 * m12 + x2 * m22;
        ushort4 u;
        u.x = __half_as_ushort(__float2half_rn(v0));
        u.y = __half_as_ushort(__float2half_rn(v1));
        u.z = __half_as_ushort(__float2half_rn(v2));
        u.w = 0;
        xmp[i] = u;
    }
}

// R15 bin: single-pass direct staging — ONE LDS atomic per edge.
// stage[b][r] fixed capacity 16; overflow -> global-cursor slow path (~0.5%).
// No histogram, no scan, edges read once.
__global__ __launch_bounds__(512) void bin_kernel(const int* __restrict__ edge_src,
                                                  const int* __restrict__ edge_dst,
                                                  int* __restrict__ bucketFill,
                                                  unsigned int* __restrict__ records) {
    __shared__ int cnt[NBUCK];                        // 4 KB: per-bucket cursor
    __shared__ unsigned int stage[NBUCK * CAP_S];     // 64 KB

    const int t = threadIdx.x;
    const long e0 = (long)blockIdx.x * CHUNK;
    const iv4* __restrict__ dst4 = reinterpret_cast<const iv4*>(edge_dst + e0);
    const iv4* __restrict__ src4 = reinterpret_cast<const iv4*>(edge_src + e0);

    for (int b = t; b < NBUCK; b += 512) cnt[b] = 0;
    __syncthreads();

    // single pass: stage records (1 LDS atomic each); overflow -> global
    for (int i = t; i < CHUNK / 4; i += 512) {
        iv4 d = __builtin_nontemporal_load(dst4 + i);
        iv4 s = __builtin_nontemporal_load(src4 + i);
        int dd[4] = { d.x, d.y, d.z, d.w };
        int ss[4] = { s.x, s.y, s.z, s.w };
        #pragma unroll
        for (int k = 0; k < 4; ++k) {
            int b = dd[k] >> BUCKET_SHIFT;
            unsigned int rec = ((unsigned int)(dd[k] & (BUCKET_NODES - 1)) << 20) | (unsigned int)ss[k];
            int r = atomicAdd(&cnt[b], 1);
            if (r < CAP_S) {
                stage[b * CAP_S + r] = rec;
            } else {
                int pos = atomicAdd(&bucketFill[b], 1);
                if (pos < CAP)
                    __builtin_nontemporal_store(rec, &records[(size_t)b * CAP + pos]);
            }
        }
    }
    __syncthreads();

    // copy out: 16-lane group per bucket; one bulk reservation per bucket
    const int wv = t >> 6, ln = t & 63;
    const int grp = ln >> 4, q = ln & 15;
    for (int b = wv * 4 + grp; b < NBUCK; b += 32) {
        int c = cnt[b];
        if (c > CAP_S) c = CAP_S;
        int g = 0;
        if (q == 0 && c > 0) g = atomicAdd(&bucketFill[b], c);
        g = __shfl(g, ln & 48);   // broadcast from lane grp*16
        for (int i = q; i < c; i += 16) {
            int pos = g + i;
            if (pos < CAP)
                __builtin_nontemporal_store(stage[b * CAP_S + i], &records[(size_t)b * CAP + pos]);
        }
    }
}

// One block (1024 thr) per bucket: R13 body verbatim (182 µs measured) —
// 2 LDS atomics per record: ds_pk_add_f16 (v0,v1) + f32 (v2).
__global__ __launch_bounds__(1024) void bucket_kernel(const unsigned int* __restrict__ records,
                                                      const int* __restrict__ bucketFill,
                                                      const ushort4* __restrict__ xmp,
                                                      const float* __restrict__ x,
                                                      const float* __restrict__ W,
                                                      double* __restrict__ sums) {
    __shared__ unsigned int aggH2[BUCKET_NODES];  // 2 KB: packed f16 (v0,v1)
    __shared__ float        aggV2[BUCKET_NODES];  // 2 KB: v2 (f32)
    __shared__ float        partw[16][3];

    const int b = blockIdx.x;
    const int t = threadIdx.x;
    const unsigned long long* __restrict__ xmp8 = (const unsigned long long*)xmp;

    for (int i = t; i < BUCKET_NODES; i += 1024) {
        aggH2[i] = 0u;
        aggV2[i] = 0.0f;
    }
    __syncthreads();

    int cnt = bucketFill[b];
    if (cnt > CAP) cnt = CAP;
    const unsigned int* __restrict__ rec = records + (size_t)b * CAP;
    const uv4* __restrict__ rec4 = reinterpret_cast<const uv4*>(rec);

    const int n4 = cnt >> 2;
    for (int i = t; i < n4; i += 1024) {
        uv4 r = __builtin_nontemporal_load(rec4 + i);
        unsigned int rr[4] = { r.x, r.y, r.z, r.w };
        unsigned long long g[4];
        #pragma unroll
        for (int k = 0; k < 4; ++k) g[k] = xmp8[rr[k] & 0xFFFFFu];
        __builtin_amdgcn_sched_barrier(0);   // keep all 4 gathers in flight
        #pragma unroll
        for (int k = 0; k < 4; ++k) {
            int dl = (int)(rr[k] >> 20);
            lds_pk_add_f16(&aggH2[dl], (unsigned int)(g[k] & 0xFFFFFFFFull));
            float v2 = __half2float(__ushort_as_half((unsigned short)((g[k] >> 32) & 0xFFFF)));
            atomicAdd(&aggV2[dl], v2);
        }
    }
    for (int i = (n4 << 2) + t; i < cnt; i += 1024) {
        unsigned int r = rec[i];
        unsigned long long g = xmp8[r & 0xFFFFFu];
        int dl = (int)(r >> 20);
        lds_pk_add_f16(&aggH2[dl], (unsigned int)(g & 0xFFFFFFFFull));
        float v2 = __half2float(__ushort_as_half((unsigned short)((g >> 32) & 0xFFFF)));
        atomicAdd(&aggV2[dl], v2);
    }
    __syncthreads();

    // fused epilogue: h = relu(x@W + agg), block partial sum (one node per thread t<512)
    float s0 = 0.0f, s1 = 0.0f, s2 = 0.0f;
    if (t < BUCKET_NODES) {
        int node = (b << BUCKET_SHIFT) + t;
        if (node < N_NODES) {
            float w00 = W[0], w01 = W[1], w02 = W[2];
            float w10 = W[3], w11 = W[4], w12 = W[5];
            float w20 = W[6], w21 = W[7], w22 = W[8];
            float x0 = x[node * 3 + 0], x1 = x[node * 3 + 1], x2 = x[node * 3 + 2];
            unsigned int u = aggH2[t];
            float a0 = __half2float(__ushort_as_half((unsigned short)(u & 0xFFFF)));
            float a1 = __half2float(__ushort_as_half((unsigned short)(u >> 16)));
            float a2f = aggV2[t];
            float t0 = x0 * w00 + x1 * w10 + x2 * w20 + a0;
            float t1 = x0 * w01 + x1 * w11 + x2 * w21 + a1;
            float t2 = x0 * w02 + x1 * w12 + x2 * w22 + a2f;
            s0 = t0 > 0.0f ? t0 : 0.0f;
            s1 = t1 > 0.0f ? t1 : 0.0f;
            s2 = t2 > 0.0f ? t2 : 0.0f;
        }
    }

    #pragma unroll
    for (int off = 32; off > 0; off >>= 1) {
        s0 += __shfl_down(s0, off);
        s1 += __shfl_down(s1, off);
        s2 += __shfl_down(s2, off);
    }
    int lane = t & 63, wave = t >> 6;
    if (lane == 0) { partw[wave][0] = s0; partw[wave][1] = s1; partw[wave][2] = s2; }
    __syncthreads();
    if (t == 0) {
        double d0 = 0.0, d1 = 0.0, d2 = 0.0;
        #pragma unroll
        for (int w = 0; w < 16; ++w) {
            d0 += (double)partw[w][0];
            d1 += (double)partw[w][1];
            d2 += (double)partw[w][2];
        }
        atomicAdd(&sums[0], d0);
        atomicAdd(&sums[1], d1);
        atomicAdd(&sums[2], d2);
    }
}

__global__ void softmax_kernel(const double* __restrict__ sums,
                               float* __restrict__ out) {
    if (blockIdx.x == 0 && threadIdx.x == 0) {
        double s0 = sums[0], s1 = sums[1], s2 = sums[2];
        double m = fmax(s0, fmax(s1, s2));
        double e0 = exp(s0 - m), e1 = exp(s1 - m), e2 = exp(s2 - m);
        double tt = e0 + e1 + e2;
        out[0] = (float)(e0 / tt);
        out[1] = (float)(e1 / tt);
        out[2] = (float)(e2 / tt);
    }
}

// =====================================================================
// FALLBACK PATH (proven R1 code) — used if ws_size < WS_NEEDED
// =====================================================================

__global__ void fb_precompute(const float* __restrict__ x, const float* __restrict__ M,
                              float* __restrict__ xm, float* __restrict__ agg,
                              double* __restrict__ sums) {
    int i = blockIdx.x * blockDim.x + threadIdx.x;
    if (i == 0) { sums[0] = 0.0; sums[1] = 0.0; sums[2] = 0.0; }
    if (i < N_NODES) {
        float m00 = M[0], m01 = M[1], m02 = M[2];
        float m10 = M[3], m11 = M[4], m12 = M[5];
        float m20 = M[6], m21 = M[7], m22 = M[8];
        float x0 = x[i * 3 + 0], x1 = x[i * 3 + 1], x2 = x[i * 3 + 2];
        xm[i * 3 + 0] = x0 * m00 + x1 * m10 + x2 * m20;
        xm[i * 3 + 1] = x0 * m01 + x1 * m11 + x2 * m21;
        xm[i * 3 + 2] = x0 * m02 + x1 * m12 + x2 * m22;
        agg[i * 3 + 0] = 0.0f; agg[i * 3 + 1] = 0.0f; agg[i * 3 + 2] = 0.0f;
    }
}

__global__ void fb_scatter(const int* __restrict__ edge_src, const int* __restrict__ edge_dst,
                           const float* __restrict__ xm, float* __restrict__ agg) {
    const int tid = blockIdx.x * blockDim.x + threadIdx.x;
    const int stride = gridDim.x * blockDim.x;
    const int4* src4 = reinterpret_cast<const int4*>(edge_src);
    const int4* dst4 = reinterpret_cast<const int4*>(edge_dst);
    const int n4 = N_EDGES / 4;
    for (int e = tid; e < n4; e += stride) {
        int4 s = src4[e]; int4 d = dst4[e];
        int ss[4] = { s.x, s.y, s.z, s.w };
        int dd[4] = { d.x, d.y, d.z, d.w };
        float v[4][3];
        #pragma unroll
        for (int k = 0; k < 4; ++k) {
            int bb = ss[k] * 3;
            v[k][0] = xm[bb + 0]; v[k][1] = xm[bb + 1]; v[k][2] = xm[bb + 2];
        }
        #pragma unroll
        for (int k = 0; k < 4; ++k) {
            int bb = dd[k] * 3;
            atomicAdd(&agg[bb + 0], v[k][0]);
            atomicAdd(&agg[bb + 1], v[k][1]);
            atomicAdd(&agg[bb + 2], v[k][2]);
        }
    }
}

__global__ void fb_reduce(const float* __restrict__ x, const float* __restrict__ W,
                          const float* __restrict__ agg, double* __restrict__ sums) {
    __shared__ float part[4][3];
    int i = blockIdx.x * blockDim.x + threadIdx.x;
    float h0 = 0.0f, h1 = 0.0f, h2 = 0.0f;
    if (i < N_NODES) {
        float w00 = W[0], w01 = W[1], w02 = W[2];
        float w10 = W[3], w11 = W[4], w12 = W[5];
        float w20 = W[6], w21 = W[7], w22 = W[8];
        float x0 = x[i * 3 + 0], x1 = x[i * 3 + 1], x2 = x[i * 3 + 2];
        float t0 = x0 * w00 + x1 * w10 + x2 * w20 + agg[i * 3 + 0];
        float t1 = x0 * w01 + x1 * w11 + x2 * w21 + agg[i * 3 + 1];
        float t2 = x0 * w02 + x1 * w12 + x2 * w22 + agg[i * 3 + 2];
        h0 = t0 > 0.0f ? t0 : 0.0f; h1 = t1 > 0.0f ? t1 : 0.0f; h2 = t2 > 0.0f ? t2 : 0.0f;
    }
    #pragma unroll
    for (int off = 32; off > 0; off >>= 1) {
        h0 += __shfl_down(h0, off); h1 += __shfl_down(h1, off); h2 += __shfl_down(h2, off);
    }
    int lane = threadIdx.x & 63, wave = threadIdx.x >> 6;
    if (lane == 0) { part[wave][0] = h0; part[wave][1] = h1; part[wave][2] = h2; }
    __syncthreads();
    if (threadIdx.x == 0) {
        double d0 = 0.0, d1 = 0.0, d2 = 0.0;
        #pragma unroll
        for (int w = 0; w < 4; ++w) {
            d0 += (double)part[w][0]; d1 += (double)part[w][1]; d2 += (double)part[w][2];
        }
        atomicAdd(&sums[0], d0); atomicAdd(&sums[1], d1); atomicAdd(&sums[2], d2);
    }
}

// =====================================================================

extern "C" void kernel_launch(void* const* d_in, const int* in_sizes, int n_in,
                              void* d_out, int out_size, void* d_ws, size_t ws_size,
                              hipStream_t stream) {
    const float* x        = (const float*)d_in[0];
    const float* W        = (const float*)d_in[1];
    const float* M        = (const float*)d_in[2];
    const int*   edge_src = (const int*)d_in[3];
    const int*   edge_dst = (const int*)d_in[4];
    float* out = (float*)d_out;

    char* ws = (char*)d_ws;
    const int nodeBlocks = (N_NODES + 255) / 256;

    if (ws_size >= WS_NEEDED) {
        ushort4*      xmp        = (ushort4*)(ws + XMP_OFF);
        double*       sums       = (double*)(ws + SUMS_OFF);
        int*          bucketFill = (int*)(ws + FILL_OFF);
        unsigned int* records    = (unsigned int*)(ws + REC_OFF);

        prep_kernel<<<nodeBlocks, 256, 0, stream>>>(x, M, xmp, bucketFill, sums);
        bin_kernel<<<BLOCKS_A, 512, 0, stream>>>(edge_src, edge_dst, bucketFill, records);
        bucket_kernel<<<NB, 1024, 0, stream>>>(records, bucketFill, xmp, x, W, sums);
        softmax_kernel<<<1, 1, 0, stream>>>(sums, out);
    } else {
        float*  xm   = (float*)ws;
        float*  agg  = xm + (size_t)N_NODES * 3;
        double* sums = (double*)(agg + (size_t)N_NODES * 3);

        fb_precompute<<<nodeBlocks, 256, 0, stream>>>(x, M, xm, agg, sums);
        fb_scatter<<<2048, 256, 0, stream>>>(edge_src, edge_dst, xm, agg);
        fb_reduce<<<nodeBlocks, 256, 0, stream>>>(x, W, agg, sums);
        softmax_kernel<<<1, 1, 0, stream>>>(sums, out);
    }
}

// Round 16
// 338.247 us; speedup vs baseline: 1.3204x; 1.3204x over previous
//
#include <hip/hip_runtime.h>
#include <hip/hip_fp16.h>

static constexpr int N_NODES = 500000;
static constexpr int N_EDGES = 16000000;

typedef int  iv4 __attribute__((ext_vector_type(4)));
typedef unsigned int uv4 __attribute__((ext_vector_type(4)));

// ---------- fast-path geometry (R5/R13/R14 proven) ----------
static constexpr int BUCKET_SHIFT = 9;                 // 512 nodes / bucket
static constexpr int BUCKET_NODES = 1 << BUCKET_SHIFT; // 512
static constexpr int NB = (N_NODES + BUCKET_NODES - 1) >> BUCKET_SHIFT; // 977
static constexpr int NBUCK = 1024;                     // padded pow2 for LDS arrays
static constexpr int CAP = 18432;                      // per-bucket capacity (mean 16378)
static constexpr int CHUNK = 10000;                    // edges per bin-block (staged = 40 KB)
static constexpr int BLOCKS_A = N_EDGES / CHUNK;       // 1600

// ws layout (bytes) — identical to R5/R13 (proven)
static constexpr size_t XMP_OFF  = 0;                          // ushort4[N_NODES] = 4,000,000
static constexpr size_t SUMS_OFF = 4000000;                    // double[4]
static constexpr size_t FILL_OFF = 4000064;                    // int[1024]
static constexpr size_t REC_OFF  = 4194304;                    // u32[NB*CAP] = 72,030,208
static constexpr size_t WS_NEEDED = REC_OFF + (size_t)NB * CAP * 4;  // 76,224,512

// LDS packed-f16 atomic add: ds_pk_add_f16 (gfx90a+, CDNA4) — proven R13
__device__ __forceinline__ void lds_pk_add_f16(unsigned int* gptr, unsigned int val) {
    unsigned addr = (unsigned)(size_t)(__attribute__((address_space(3))) unsigned int*)gptr;
    asm volatile("ds_pk_add_f16 %0, %1" :: "v"(addr), "v"(val) : "memory");
}

// =====================================================================
// FAST PATH
// =====================================================================

// xm(f16x4) = x @ M ; zero bucketFill and sums
__global__ void prep_kernel(const float* __restrict__ x,
                            const float* __restrict__ M,
                            ushort4* __restrict__ xmp,
                            int* __restrict__ bucketFill,
                            double* __restrict__ sums) {
    int i = blockIdx.x * blockDim.x + threadIdx.x;
    if (i < NBUCK) bucketFill[i] = 0;
    if (i == 0) { sums[0] = 0.0; sums[1] = 0.0; sums[2] = 0.0; }
    if (i < N_NODES) {
        float m00 = M[0], m01 = M[1], m02 = M[2];
        float m10 = M[3], m11 = M[4], m12 = M[5];
        float m20 = M[6], m21 = M[7], m22 = M[8];
        float x0 = x[i * 3 + 0], x1 = x[i * 3 + 1], x2 = x[i * 3 + 2];
        float v0 = x0 * m00 + x1 * m10 + x2 * m20;
        float v1 = x0 * m01 + x1 * m11 + x2 * m21;
        float v2 = x0 * m02 + x1 * m12 + x2 * m22;
        ushort4 u;
        u.x = __half_as_ushort(__float2half_rn(v0));
        u.y = __half_as_ushort(__float2half_rn(v1));
        u.z = __half_as_ushort(__float2half_rn(v2));
        u.w = 0;
        xmp[i] = u;
    }
}

// Partition edges into buckets of 512 dst nodes. 512 threads. (R14 verbatim —
// measured ~150 µs: hist + scan + cursor-stage + 16-lane-group pass-3)
__global__ __launch_bounds__(512) void bin_kernel(const int* __restrict__ edge_src,
                                                  const int* __restrict__ edge_dst,
                                                  int* __restrict__ bucketFill,
                                                  unsigned int* __restrict__ records) {
    __shared__ int cnt[NBUCK];                 // 4 KB: histogram, then cursor
    __shared__ unsigned short start[NBUCK];    // 2 KB
    __shared__ unsigned short gbase[NBUCK];    // 2 KB
    __shared__ int part[256];                  // 1 KB
    __shared__ unsigned int staged[CHUNK];     // 40 KB

    const int t = threadIdx.x;
    const long e0 = (long)blockIdx.x * CHUNK;
    const iv4* __restrict__ dst4 = reinterpret_cast<const iv4*>(edge_dst + e0);
    const iv4* __restrict__ src4 = reinterpret_cast<const iv4*>(edge_src + e0);

    for (int b = t; b < NBUCK; b += 512) cnt[b] = 0;
    __syncthreads();

    // pass 1: histogram of dst buckets (nt int4 loads)
    for (int i = t; i < CHUNK / 4; i += 512) {
        iv4 d = __builtin_nontemporal_load(dst4 + i);
        atomicAdd(&cnt[d.x >> BUCKET_SHIFT], 1);
        atomicAdd(&cnt[d.y >> BUCKET_SHIFT], 1);
        atomicAdd(&cnt[d.z >> BUCKET_SHIFT], 1);
        atomicAdd(&cnt[d.w >> BUCKET_SHIFT], 1);
    }
    __syncthreads();

    // exclusive scan of cnt[0..1023] -> start[] (threads 0..255 drive)
    int a0 = 0, a1 = 0, a2 = 0, a3 = 0, tsum = 0;
    if (t < 256) {
        a0 = cnt[4 * t + 0]; a1 = cnt[4 * t + 1]; a2 = cnt[4 * t + 2]; a3 = cnt[4 * t + 3];
        tsum = a0 + a1 + a2 + a3;
        part[t] = tsum;
    }
    __syncthreads();
    for (int off = 1; off < 256; off <<= 1) {
        int u = 0, v = 0;
        if (t < 256) { u = part[t]; v = (t >= off) ? part[t - off] : 0; }
        __syncthreads();
        if (t < 256) part[t] = u + v;
        __syncthreads();
    }
    if (t < 256) {
        int texcl = part[t] - tsum;
        start[4 * t + 0] = (unsigned short)texcl;
        start[4 * t + 1] = (unsigned short)(texcl + a0);
        start[4 * t + 2] = (unsigned short)(texcl + a0 + a1);
        start[4 * t + 3] = (unsigned short)(texcl + a0 + a1 + a2);
    }
    __syncthreads();

    // global reservation (rotated); then cursor = start
    for (int j = t; j < NBUCK; j += 512) {
        int b = (j + blockIdx.x * 7) & (NBUCK - 1);
        int c = cnt[b];
        gbase[b] = (unsigned short)((c > 0) ? atomicAdd(&bucketFill[b], c) : 0);
    }
    __syncthreads();
    for (int b = t; b < NBUCK; b += 512) cnt[b] = (int)start[b];
    __syncthreads();

    // pass 2: stage records grouped by bucket
    for (int i = t; i < CHUNK / 4; i += 512) {
        iv4 d = __builtin_nontemporal_load(dst4 + i);
        iv4 s = __builtin_nontemporal_load(src4 + i);
        int dd[4] = { d.x, d.y, d.z, d.w };
        int ss[4] = { s.x, s.y, s.z, s.w };
        #pragma unroll
        for (int k = 0; k < 4; ++k) {
            int b = dd[k] >> BUCKET_SHIFT;
            int r = atomicAdd(&cnt[b], 1);
            staged[r] = ((unsigned int)(dd[k] & (BUCKET_NODES - 1)) << 20) | (unsigned int)ss[k];
        }
    }
    __syncthreads();

    // pass 3: 16-lane-group-per-bucket copy (32 buckets in flight)
    const int wv = t >> 6, ln = t & 63;
    const int grp = ln >> 4, q = ln & 15;
    for (int b = wv * 4 + grp; b < NBUCK; b += 32) {
        int s0 = (int)start[b];
        int c  = cnt[b] - s0;
        int g  = (int)gbase[b];
        for (int i = q; i < c; i += 16) {
            int pos = g + i;
            if (pos < CAP)
                __builtin_nontemporal_store(staged[s0 + i], &records[(size_t)b * CAP + pos]);
        }
    }
}

// One block (1024 thr) per bucket: R13 body verbatim (182 µs measured) —
// 2 LDS atomics per record: ds_pk_add_f16 (v0,v1) + f32 (v2).
__global__ __launch_bounds__(1024) void bucket_kernel(const unsigned int* __restrict__ records,
                                                      const int* __restrict__ bucketFill,
                                                      const ushort4* __restrict__ xmp,
                                                      const float* __restrict__ x,
                                                      const float* __restrict__ W,
                                                      double* __restrict__ sums) {
    __shared__ unsigned int aggH2[BUCKET_NODES];  // 2 KB: packed f16 (v0,v1)
    __shared__ float        aggV2[BUCKET_NODES];  // 2 KB: v2 (f32)
    __shared__ float        partw[16][3];

    const int b = blockIdx.x;
    const int t = threadIdx.x;
    const unsigned long long* __restrict__ xmp8 = (const unsigned long long*)xmp;

    for (int i = t; i < BUCKET_NODES; i += 1024) {
        aggH2[i] = 0u;
        aggV2[i] = 0.0f;
    }
    __syncthreads();

    int cnt = bucketFill[b];
    if (cnt > CAP) cnt = CAP;
    const unsigned int* __restrict__ rec = records + (size_t)b * CAP;
    const uv4* __restrict__ rec4 = reinterpret_cast<const uv4*>(rec);

    const int n4 = cnt >> 2;
    for (int i = t; i < n4; i += 1024) {
        uv4 r = __builtin_nontemporal_load(rec4 + i);
        unsigned int rr[4] = { r.x, r.y, r.z, r.w };
        unsigned long long g[4];
        #pragma unroll
        for (int k = 0; k < 4; ++k) g[k] = xmp8[rr[k] & 0xFFFFFu];
        __builtin_amdgcn_sched_barrier(0);   // keep all 4 gathers in flight
        #pragma unroll
        for (int k = 0; k < 4; ++k) {
            int dl = (int)(rr[k] >> 20);
            lds_pk_add_f16(&aggH2[dl], (unsigned int)(g[k] & 0xFFFFFFFFull));
            float v2 = __half2float(__ushort_as_half((unsigned short)((g[k] >> 32) & 0xFFFF)));
            atomicAdd(&aggV2[dl], v2);
        }
    }
    for (int i = (n4 << 2) + t; i < cnt; i += 1024) {
        unsigned int r = rec[i];
        unsigned long long g = xmp8[r & 0xFFFFFu];
        int dl = (int)(r >> 20);
        lds_pk_add_f16(&aggH2[dl], (unsigned int)(g & 0xFFFFFFFFull));
        float v2 = __half2float(__ushort_as_half((unsigned short)((g >> 32) & 0xFFFF)));
        atomicAdd(&aggV2[dl], v2);
    }
    __syncthreads();

    // fused epilogue: h = relu(x@W + agg), block partial sum (one node per thread t<512)
    float s0 = 0.0f, s1 = 0.0f, s2 = 0.0f;
    if (t < BUCKET_NODES) {
        int node = (b << BUCKET_SHIFT) + t;
        if (node < N_NODES) {
            float w00 = W[0], w01 = W[1], w02 = W[2];
            float w10 = W[3], w11 = W[4], w12 = W[5];
            float w20 = W[6], w21 = W[7], w22 = W[8];
            float x0 = x[node * 3 + 0], x1 = x[node * 3 + 1], x2 = x[node * 3 + 2];
            unsigned int u = aggH2[t];
            float a0 = __half2float(__ushort_as_half((unsigned short)(u & 0xFFFF)));
            float a1 = __half2float(__ushort_as_half((unsigned short)(u >> 16)));
            float a2f = aggV2[t];
            float t0 = x0 * w00 + x1 * w10 + x2 * w20 + a0;
            float t1 = x0 * w01 + x1 * w11 + x2 * w21 + a1;
            float t2 = x0 * w02 + x1 * w12 + x2 * w22 + a2f;
            s0 = t0 > 0.0f ? t0 : 0.0f;
            s1 = t1 > 0.0f ? t1 : 0.0f;
            s2 = t2 > 0.0f ? t2 : 0.0f;
        }
    }

    #pragma unroll
    for (int off = 32; off > 0; off >>= 1) {
        s0 += __shfl_down(s0, off);
        s1 += __shfl_down(s1, off);
        s2 += __shfl_down(s2, off);
    }
    int lane = t & 63, wave = t >> 6;
    if (lane == 0) { partw[wave][0] = s0; partw[wave][1] = s1; partw[wave][2] = s2; }
    __syncthreads();
    if (t == 0) {
        double d0 = 0.0, d1 = 0.0, d2 = 0.0;
        #pragma unroll
        for (int w = 0; w < 16; ++w) {
            d0 += (double)partw[w][0];
            d1 += (double)partw[w][1];
            d2 += (double)partw[w][2];
        }
        atomicAdd(&sums[0], d0);
        atomicAdd(&sums[1], d1);
        atomicAdd(&sums[2], d2);
    }
}

__global__ void softmax_kernel(const double* __restrict__ sums,
                               float* __restrict__ out) {
    if (blockIdx.x == 0 && threadIdx.x == 0) {
        double s0 = sums[0], s1 = sums[1], s2 = sums[2];
        double m = fmax(s0, fmax(s1, s2));
        double e0 = exp(s0 - m), e1 = exp(s1 - m), e2 = exp(s2 - m);
        double tt = e0 + e1 + e2;
        out[0] = (float)(e0 / tt);
        out[1] = (float)(e1 / tt);
        out[2] = (float)(e2 / tt);
    }
}

// =====================================================================
// FALLBACK PATH (proven R1 code) — used if ws_size < WS_NEEDED
// =====================================================================

__global__ void fb_precompute(const float* __restrict__ x, const float* __restrict__ M,
                              float* __restrict__ xm, float* __restrict__ agg,
                              double* __restrict__ sums) {
    int i = blockIdx.x * blockDim.x + threadIdx.x;
    if (i == 0) { sums[0] = 0.0; sums[1] = 0.0; sums[2] = 0.0; }
    if (i < N_NODES) {
        float m00 = M[0], m01 = M[1], m02 = M[2];
        float m10 = M[3], m11 = M[4], m12 = M[5];
        float m20 = M[6], m21 = M[7], m22 = M[8];
        float x0 = x[i * 3 + 0], x1 = x[i * 3 + 1], x2 = x[i * 3 + 2];
        xm[i * 3 + 0] = x0 * m00 + x1 * m10 + x2 * m20;
        xm[i * 3 + 1] = x0 * m01 + x1 * m11 + x2 * m21;
        xm[i * 3 + 2] = x0 * m02 + x1 * m12 + x2 * m22;
        agg[i * 3 + 0] = 0.0f; agg[i * 3 + 1] = 0.0f; agg[i * 3 + 2] = 0.0f;
    }
}

__global__ void fb_scatter(const int* __restrict__ edge_src, const int* __restrict__ edge_dst,
                           const float* __restrict__ xm, float* __restrict__ agg) {
    const int tid = blockIdx.x * blockDim.x + threadIdx.x;
    const int stride = gridDim.x * blockDim.x;
    const int4* src4 = reinterpret_cast<const int4*>(edge_src);
    const int4* dst4 = reinterpret_cast<const int4*>(edge_dst);
    const int n4 = N_EDGES / 4;
    for (int e = tid; e < n4; e += stride) {
        int4 s = src4[e]; int4 d = dst4[e];
        int ss[4] = { s.x, s.y, s.z, s.w };
        int dd[4] = { d.x, d.y, d.z, d.w };
        float v[4][3];
        #pragma unroll
        for (int k = 0; k < 4; ++k) {
            int bb = ss[k] * 3;
            v[k][0] = xm[bb + 0]; v[k][1] = xm[bb + 1]; v[k][2] = xm[bb + 2];
        }
        #pragma unroll
        for (int k = 0; k < 4; ++k) {
            int bb = dd[k] * 3;
            atomicAdd(&agg[bb + 0], v[k][0]);
            atomicAdd(&agg[bb + 1], v[k][1]);
            atomicAdd(&agg[bb + 2], v[k][2]);
        }
    }
}

__global__ void fb_reduce(const float* __restrict__ x, const float* __restrict__ W,
                          const float* __restrict__ agg, double* __restrict__ sums) {
    __shared__ float part[4][3];
    int i = blockIdx.x * blockDim.x + threadIdx.x;
    float h0 = 0.0f, h1 = 0.0f, h2 = 0.0f;
    if (i < N_NODES) {
        float w00 = W[0], w01 = W[1], w02 = W[2];
        float w10 = W[3], w11 = W[4], w12 = W[5];
        float w20 = W[6], w21 = W[7], w22 = W[8];
        float x0 = x[i * 3 + 0], x1 = x[i * 3 + 1], x2 = x[i * 3 + 2];
        float t0 = x0 * w00 + x1 * w10 + x2 * w20 + agg[i * 3 + 0];
        float t1 = x0 * w01 + x1 * w11 + x2 * w21 + agg[i * 3 + 1];
        float t2 = x0 * w02 + x1 * w12 + x2 * w22 + agg[i * 3 + 2];
        h0 = t0 > 0.0f ? t0 : 0.0f; h1 = t1 > 0.0f ? t1 : 0.0f; h2 = t2 > 0.0f ? t2 : 0.0f;
    }
    #pragma unroll
    for (int off = 32; off > 0; off >>= 1) {
        h0 += __shfl_down(h0, off); h1 += __shfl_down(h1, off); h2 += __shfl_down(h2, off);
    }
    int lane = threadIdx.x & 63, wave = threadIdx.x >> 6;
    if (lane == 0) { part[wave][0] = h0; part[wave][1] = h1; part[wave][2] = h2; }
    __syncthreads();
    if (threadIdx.x == 0) {
        double d0 = 0.0, d1 = 0.0, d2 = 0.0;
        #pragma unroll
        for (int w = 0; w < 4; ++w) {
            d0 += (double)part[w][0]; d1 += (double)part[w][1]; d2 += (double)part[w][2];
        }
        atomicAdd(&sums[0], d0); atomicAdd(&sums[1], d1); atomicAdd(&sums[2], d2);
    }
}

// =====================================================================

extern "C" void kernel_launch(void* const* d_in, const int* in_sizes, int n_in,
                              void* d_out, int out_size, void* d_ws, size_t ws_size,
                              hipStream_t stream) {
    const float* x        = (const float*)d_in[0];
    const float* W        = (const float*)d_in[1];
    const float* M        = (const float*)d_in[2];
    const int*   edge_src = (const int*)d_in[3];
    const int*   edge_dst = (const int*)d_in[4];
    float* out = (float*)d_out;

    char* ws = (char*)d_ws;
    const int nodeBlocks = (N_NODES + 255) / 256;

    if (ws_size >= WS_NEEDED) {
        ushort4*      xmp        = (ushort4*)(ws + XMP_OFF);
        double*       sums       = (double*)(ws + SUMS_OFF);
        int*          bucketFill = (int*)(ws + FILL_OFF);
        unsigned int* records    = (unsigned int*)(ws + REC_OFF);

        prep_kernel<<<nodeBlocks, 256, 0, stream>>>(x, M, xmp, bucketFill, sums);
        bin_kernel<<<BLOCKS_A, 512, 0, stream>>>(edge_src, edge_dst, bucketFill, records);
        bucket_kernel<<<NB, 1024, 0, stream>>>(records, bucketFill, xmp, x, W, sums);
        softmax_kernel<<<1, 1, 0, stream>>>(sums, out);
    } else {
        float*  xm   = (float*)ws;
        float*  agg  = xm + (size_t)N_NODES * 3;
        double* sums = (double*)(agg + (size_t)N_NODES * 3);

        fb_precompute<<<nodeBlocks, 256, 0, stream>>>(x, M, xm, agg, sums);
        fb_scatter<<<2048, 256, 0, stream>>>(edge_src, edge_dst, xm, agg);
        fb_reduce<<<nodeBlocks, 256, 0, stream>>>(x, W, agg, sums);
        softmax_kernel<<<1, 1, 0, stream>>>(sums, out);
    }
}